// Round 5
// baseline (166.434 us; speedup 1.0000x reference)
//
#include <hip/hip_runtime.h>
#include <cmath>

namespace {

typedef _Float16 half8_t __attribute__((ext_vector_type(8)));
typedef _Float16 half4_t __attribute__((ext_vector_type(4)));
typedef float    f32x4_t __attribute__((ext_vector_type(4)));

constexpr int R_ = 8, M1_ = 32, N1_ = 64, M2_ = 24, N2_ = 48;
constexpr int DIN = 768;          // M1*M2
constexpr int T_TOK = 4;          // tokens per workgroup
constexpr int NTHREADS = 512;     // 8 waves

// ---- LDS layout, 52736 B -> 3 blocks/CU (3x52736 = 158208 <= 163840).
// Phase A: XP + T1 dbuf (40960 B). Phase B: HG + ZP (52736 B), overlapping.
// Final OUT (f32 [768][9] = 27648 B) overlaps dead HG at offset 0.
constexpr int XP_H   = 0;         // [128][40] f16
constexpr int T1_H   = 5120;      // 2 x [192][40] f16
constexpr int T1_BUF = 7680;
constexpr int HG_H   = 0;         // [192][72] f16 (phase B)
constexpr int ZP_H   = 13824;     // [32][392] f16
constexpr int OUT_F  = 0;         // f32-element offset: [768][9] f32 (after tt loop)
constexpr int LDS_BYTES = 52736;

// 8 contiguous fp32 -> f16 fragment, scaled by 2^6 (exact)
__device__ inline half8_t cvt8c(const float* __restrict__ p) {
    const f32x4_t a = *(const f32x4_t*)p;
    const f32x4_t b = *(const f32x4_t*)(p + 4);
    half8_t h;
    #pragma unroll
    for (int i = 0; i < 4; ++i) {
        h[i]     = (_Float16)(a[i] * 64.0f);
        h[4 + i] = (_Float16)(b[i] * 64.0f);
    }
    return h;
}

__global__ __launch_bounds__(NTHREADS, 6)   // 6 waves/SIMD = 3 blocks/CU
void kn_mfma(const float* __restrict__ x,
             const float* __restrict__ A1,
             const float* __restrict__ B1,
             const float* __restrict__ A2,
             const float* __restrict__ B2,
             const float* __restrict__ b1,
             const float* __restrict__ b2,
             const int* __restrict__ p_inv,
             const int* __restrict__ q,
             float* __restrict__ out)
{
    extern __shared__ char smem[];
    _Float16* ldsH = (_Float16*)smem;
    float*    ldsF = (float*)smem;

    const int tid  = threadIdx.x;
    const int lane = tid & 63;
    const int w    = __builtin_amdgcn_readfirstlane(tid >> 6);  // uniform wave id
    const int quad = lane >> 4;
    const int l16  = lane & 15;

    const long tokBase = (long)blockIdx.x * T_TOK;
    // p_inv/q may be int64 or int32; a permutation can't have two zeros.
    const bool idx64 = (p_inv[1] == 0 && p_inv[3] == 0);

    // ---------------- fill XPh[(t*32+i)][m2] = f16(x[t][p_inv[i*24+m2]]) -----
    {
        const int t = tid >> 7, col = tid & 127;
        const float* xrow = x + (size_t)(tokBase + t) * DIN;
        #pragma unroll
        for (int c = 0; c < 6; ++c) {
            const int kIdx = c * 128 + col;
            const int pidx = idx64 ? p_inv[2 * kIdx] : p_inv[kIdx];
            const int i = kIdx / 24, m2 = kIdx - i * 24;
            ldsH[XP_H + (t * 32 + i) * 40 + m2] = (_Float16)xrow[pidx];
        }
        // zero k-pad cols [24,40) so MFMA K=32 reads zeros beyond m2=24
        const int r0 = tid >> 2, c0 = 24 + (tid & 3) * 4;
        *(half4_t*)&ldsH[XP_H + r0 * 40 + c0] = half4_t{0, 0, 0, 0};
    }
    __syncthreads();

    const f32x4_t zero4 = {0.f, 0.f, 0.f, 0.f};

    // stage-1 A fragment is invariant across r: load once. A[m=(t,i)][k=m2]
    const half8_t xp_frag = *(const half8_t*)&ldsH[XP_H + (16 * w + l16) * 40 + quad * 8];
    const int s1_t  = (16 * w + quad * 4) >> 5;   // token (uniform per wave-half)
    const int s1_i0 = (16 * w + quad * 4) & 31;   // 4-aligned i base

    // stage-2 accumulators: h*2^12, 6 tiles/wave (row-tile w&3, cols (w>>2)+2u)
    f32x4_t hacc[6];
    #pragma unroll
    for (int u = 0; u < 6; ++u) hacc[u] = zero4;

    auto stage1 = [&](int rr) {   // T1_r[(t,i)][j] = XP * (B1_r*64), f16 out
        _Float16* t1 = ldsH + T1_H + (rr & 1) * T1_BUF;
        #pragma unroll
        for (int ct = 0; ct < 3; ++ct) {
            // bf[n=j][k=m2]: B1 native is [r][k][j] -> 8 j-coalesced strided
            // dwords (4 x 64B segments per instr); k>=24 pad -> quad 3 zeroed.
            half8_t bf;
            #pragma unroll
            for (int z = 0; z < 8; ++z) bf[z] = (_Float16)0.f;
            if (quad < 3) {
                const float* p = B1 + ((size_t)rr * M2_ + quad * 8) * N2_ + ct * 16 + l16;
                #pragma unroll
                for (int kk = 0; kk < 8; ++kk)
                    bf[kk] = (_Float16)(p[kk * N2_] * 64.0f);
            }
            f32x4_t c = __builtin_amdgcn_mfma_f32_16x16x32_f16(xp_frag, bf, zero4, 0, 0, 0);
            half4_t pk;
            pk[0] = (_Float16)c[0]; pk[1] = (_Float16)c[1];
            pk[2] = (_Float16)c[2]; pk[3] = (_Float16)c[3];
            const int s = s1_t * 48 + ct * 16 + l16;        // (t,j) row of T1T
            *(half4_t*)&t1[s * 40 + s1_i0] = pk;            // 4 consecutive i
        }
    };

    auto stage2 = [&](int rr) {   // hacc += (A1_r*64) * T1_r
        const _Float16* t1 = ldsH + T1_H + (rr & 1) * T1_BUF;
        // af[n1][k=i]: A1 native [r][n1][i] is i-contiguous -> 2 dwordx4 + cvt
        const half8_t af = cvt8c(A1 + ((size_t)rr * N1_ + (w & 3) * 16 + l16) * M1_ + quad * 8);
        #pragma unroll
        for (int u = 0; u < 6; ++u) {
            const int ct = (w >> 2) + 2 * u;
            const half8_t bf = *(const half8_t*)&t1[(ct * 16 + l16) * 40 + quad * 8];
            hacc[u] = __builtin_amdgcn_mfma_f32_16x16x32_f16(af, bf, hacc[u], 0, 0, 0);
        }
    };

    // ---------------- phase A: 1 barrier per r, T1 double-buffered -----------
    stage1(0);
    __syncthreads();
    for (int r = 0; r < R_; ++r) {
        stage2(r);
        if (r + 1 < R_) stage1(r + 1);
        __syncthreads();
    }

    // ---------------- epilogue 1: h = hacc/4096 + b1; Hg = gelu(h)*4096 ------
    {
        const float inv4096 = 1.0f / 4096.0f;
        #pragma unroll
        for (int u = 0; u < 6; ++u) {
            const int ct = (w >> 2) + 2 * u;
            const int s  = ct * 16 + l16;           // (t,n2)
            const int n2 = s % 48;
            const int n1b = (w & 3) * 16 + quad * 4;
            half4_t p;
            #pragma unroll
            for (int rg = 0; rg < 4; ++rg) {
                const float hv = hacc[u][rg] * inv4096 + b1[(n1b + rg) * 48 + n2];
                float g;
                if (__builtin_expect(fabsf(hv) < 0.04f, 1)) {
                    g = fmaf(0.3989422804f * hv, hv, 0.5f * hv);  // |err| = O(h^4)
                } else {
                    g = 0.5f * hv * (1.0f + erff(hv * 0.70710678118654752f));
                }
                p[rg] = (_Float16)(g * 4096.0f);
            }
            *(half4_t*)&ldsH[HG_H + s * 72 + n1b] = p;   // HgT[(t,n2)][n1]
        }
    }

    // ---------------- hoisted phase-B weight fragments (register-resident) ---
    const int kh  = w >> 2;        // stage-4 k-half (r 0..3 | 4..7)
    const int rt4 = (w >> 1) & 1;  // stage-4 m1 tile
    const int ct4 = w & 1;         // stage-4 m2 tile

    // stage-3 af: A2 native [r][m1][n1] is n1-contiguous; wave w owns r=w.
    half8_t w3f[2][2];
    #pragma unroll
    for (int e = 0; e < 2; ++e)
        #pragma unroll
        for (int kk = 0; kk < 2; ++kk)
            w3f[e][kk] = cvt8c(A2 + ((size_t)w * M1_ + e * 16 + l16) * N1_ + kk * 32 + quad * 8);

    // stage-4 bf[m2][k=r*48+n2]: B2 native [r][n2][m2] -> strided dwords,
    // m2-coalesced across lanes; m2>=24 lanes zeroed (pad columns, discarded).
    half8_t w4f[6];
    {
        const int m2c = ct4 * 16 + l16;
        #pragma unroll
        for (int kk = 0; kk < 6; ++kk) {
            #pragma unroll
            for (int z = 0; z < 8; ++z) w4f[kk][z] = (_Float16)0.f;
            if (m2c < M2_) {
                const float* p = B2 + ((size_t)kh * 192 + kk * 32 + quad * 8) * M2_ + m2c;
                #pragma unroll
                for (int j2 = 0; j2 < 8; ++j2)
                    w4f[kk][j2] = (_Float16)(p[j2 * M2_] * 64.0f);
            }
        }
    }
    __syncthreads();

    // ---------------- phase B per token: Z' = (A2*64)*Hg' ; oc4 += Z'*B2' ----
    // stage-4 partials stay in registers across the token loop (f32x4 x 4);
    // OUT materializes once at the end, overlapping the dead HG region.
    f32x4_t oc4[T_TOK];
    #pragma unroll
    for (int tt = 0; tt < T_TOK; ++tt) oc4[tt] = zero4;

    #pragma unroll
    for (int tt = 0; tt < T_TOK; ++tt) {
        // stage 3: wave w owns r=w rows of Z'. 6 tiles x K=64.
        f32x4_t zc[6];
        #pragma unroll
        for (int u = 0; u < 6; ++u) zc[u] = zero4;
        #pragma unroll
        for (int e = 0; e < 2; ++e)
            #pragma unroll
            for (int ct = 0; ct < 3; ++ct) {
                const int u = e * 3 + ct;
                #pragma unroll
                for (int kk = 0; kk < 2; ++kk) {
                    const half8_t bf = *(const half8_t*)&ldsH[HG_H + (tt * 48 + ct * 16 + l16) * 72 + kk * 32 + quad * 8];
                    zc[u] = __builtin_amdgcn_mfma_f32_16x16x32_f16(w3f[e][kk], bf, zc[u], 0, 0, 0);
                }
            }
        // scatter C -> A-layout Z'[m1][r*48+n2] (f16 writes; 2-way max)
        #pragma unroll
        for (int e = 0; e < 2; ++e)
            #pragma unroll
            for (int ct = 0; ct < 3; ++ct) {
                const int u = e * 3 + ct;
                const int kcol = w * 48 + ct * 16 + l16;
                #pragma unroll
                for (int rg = 0; rg < 4; ++rg)
                    ldsH[ZP_H + (16 * e + quad * 4 + rg) * 392 + kcol] = (_Float16)(zc[u][rg]);
            }
        __syncthreads();

        // stage 4: oc4[tt] = Z' * B2'; wave = (kh, rt4, ct4); K-half = 192
        #pragma unroll
        for (int kk = 0; kk < 6; ++kk) {
            const int k0 = kh * 192 + kk * 32;
            const half8_t af = *(const half8_t*)&ldsH[ZP_H + (rt4 * 16 + l16) * 392 + k0 + quad * 8];
            oc4[tt] = __builtin_amdgcn_mfma_f32_16x16x32_f16(af, w4f[kk], oc4[tt], 0, 0, 0);
        }
        if (tt + 1 < T_TOK) __syncthreads();   // protect Z' rewrite next tt
    }

    // ---------------- OUT write (HG dead since tt=3 scatter barrier) ---------
    {
        const int m2c = ct4 * 16 + l16;
        if (m2c < M2_) {
            #pragma unroll
            for (int tt = 0; tt < T_TOK; ++tt)
                #pragma unroll
                for (int rg = 0; rg < 4; ++rg) {
                    const int m1 = rt4 * 16 + quad * 4 + rg;
                    ldsF[OUT_F + (m1 * M2_ + m2c) * 9 + tt * 2 + kh] = oc4[tt][rg];
                }
        }
    }
    __syncthreads();

    // ---------------- final: sum k-halves, /2^24, +b2, q-gather, store -------
    {
        const int t = tid >> 7, col = tid & 127;
        float* orow = out + (size_t)(tokBase + t) * DIN;
        const float sc = 1.0f / 16777216.0f;
        #pragma unroll
        for (int c = 0; c < 6; ++c) {
            const int j  = c * 128 + col;
            const int qj = idx64 ? q[2 * j] : q[j];
            orow[j] = (ldsF[OUT_F + qj * 9 + t * 2] + ldsF[OUT_F + qj * 9 + t * 2 + 1]) * sc + b2[qj];
        }
    }
}

} // namespace

extern "C" void kernel_launch(void* const* d_in, const int* in_sizes, int n_in,
                              void* d_out, int out_size, void* d_ws, size_t ws_size,
                              hipStream_t stream) {
    const float* x   = (const float*)d_in[0];
    const float* A1  = (const float*)d_in[1];
    const float* B1  = (const float*)d_in[2];
    const float* A2  = (const float*)d_in[3];
    const float* B2  = (const float*)d_in[4];
    const float* b1  = (const float*)d_in[5];
    const float* b2  = (const float*)d_in[6];
    const int*   piv = (const int*)d_in[7];
    const int*   q   = (const int*)d_in[8];
    float* out = (float*)d_out;

    const int tokens = in_sizes[0] / DIN;          // 4096
    const int grid   = tokens / T_TOK;             // 1024

    (void)hipFuncSetAttribute((const void*)kn_mfma,
                              hipFuncAttributeMaxDynamicSharedMemorySize,
                              LDS_BYTES);
    kn_mfma<<<grid, NTHREADS, LDS_BYTES, stream>>>(x, A1, B1, A2, B2, b1, b2, piv, q, out);
}

// Round 6
// 137.805 us; speedup vs baseline: 1.2078x; 1.2078x over previous
//
#include <hip/hip_runtime.h>
#include <cmath>

namespace {

typedef _Float16 half8_t __attribute__((ext_vector_type(8)));
typedef _Float16 half4_t __attribute__((ext_vector_type(4)));
typedef float    f32x4_t __attribute__((ext_vector_type(4)));

constexpr int R_ = 8, M1_ = 32, N1_ = 64, M2_ = 24, N2_ = 48;
constexpr int DIN = 768;          // M1*M2
constexpr int T_TOK = 4;          // tokens per workgroup
constexpr int NTHREADS = 512;     // 8 waves

// ---- LDS layout, 52736 B -> 3 blocks/CU (3x52736 = 158208 <= 163840).
// Phase A: XP + T1 dbuf (40960 B). Phase B: HG + ZP (52736 B, overlapping).
// Per-token stage-4 partials (768x2 f32 = 6144 B) reuse the HG quarter of
// that token (6912 B), which is dead after its last stage-3 read.
constexpr int XP_H   = 0;         // [128][40] f16
constexpr int T1_H   = 5120;      // 2 x [192][40] f16
constexpr int T1_BUF = 7680;
constexpr int HG_H   = 0;         // [192][72] f16 (phase B); quarter tt = rows [48tt,48tt+48)
constexpr int ZP_H   = 13824;     // [32][392] f16
constexpr int LDS_BYTES = 52736;

// 8 contiguous fp32 -> f16 fragment, scaled by 2^6 (exact)
__device__ inline half8_t cvt8c(const float* __restrict__ p) {
    const f32x4_t a = *(const f32x4_t*)p;
    const f32x4_t b = *(const f32x4_t*)(p + 4);
    half8_t h;
    #pragma unroll
    for (int i = 0; i < 4; ++i) {
        h[i]     = (_Float16)(a[i] * 64.0f);
        h[4 + i] = (_Float16)(b[i] * 64.0f);
    }
    return h;
}

__global__ __launch_bounds__(NTHREADS, 4)   // known-good allocator regime (52 VGPR in r4)
void kn_mfma(const float* __restrict__ x,
             const float* __restrict__ A1,
             const float* __restrict__ B1,
             const float* __restrict__ A2,
             const float* __restrict__ B2,
             const float* __restrict__ b1,
             const float* __restrict__ b2,
             const int* __restrict__ p_inv,
             const int* __restrict__ q,
             float* __restrict__ out)
{
    extern __shared__ char smem[];
    _Float16* ldsH = (_Float16*)smem;
    float*    ldsF = (float*)smem;

    const int tid  = threadIdx.x;
    const int lane = tid & 63;
    const int w    = __builtin_amdgcn_readfirstlane(tid >> 6);  // uniform wave id
    const int quad = lane >> 4;
    const int l16  = lane & 15;

    const long tokBase = (long)blockIdx.x * T_TOK;
    // p_inv/q may be int64 or int32; a permutation can't have two zeros.
    const bool idx64 = (p_inv[1] == 0 && p_inv[3] == 0);

    // ---------------- fill XPh[(t*32+i)][m2] = f16(x[t][p_inv[i*24+m2]]) -----
    {
        const int t = tid >> 7, col = tid & 127;
        const float* xrow = x + (size_t)(tokBase + t) * DIN;
        #pragma unroll
        for (int c = 0; c < 6; ++c) {
            const int kIdx = c * 128 + col;
            const int pidx = idx64 ? p_inv[2 * kIdx] : p_inv[kIdx];
            const int i = kIdx / 24, m2 = kIdx - i * 24;
            ldsH[XP_H + (t * 32 + i) * 40 + m2] = (_Float16)xrow[pidx];
        }
        // zero k-pad cols [24,40) so MFMA K=32 reads zeros beyond m2=24
        const int r0 = tid >> 2, c0 = 24 + (tid & 3) * 4;
        *(half4_t*)&ldsH[XP_H + r0 * 40 + c0] = half4_t{0, 0, 0, 0};
    }
    __syncthreads();

    const f32x4_t zero4 = {0.f, 0.f, 0.f, 0.f};

    // stage-1 A fragment is invariant across r: load once. A[m=(t,i)][k=m2]
    const half8_t xp_frag = *(const half8_t*)&ldsH[XP_H + (16 * w + l16) * 40 + quad * 8];
    const int s1_t  = (16 * w + quad * 4) >> 5;   // token (uniform per wave-half)
    const int s1_i0 = (16 * w + quad * 4) & 31;   // 4-aligned i base

    // stage-2 accumulators: h*2^12, 6 tiles/wave (row-tile w&3, cols (w>>2)+2u)
    f32x4_t hacc[6];
    #pragma unroll
    for (int u = 0; u < 6; ++u) hacc[u] = zero4;

    auto stage1 = [&](int rr) {   // T1_r[(t,i)][j] = XP * (B1_r*64), f16 out
        _Float16* t1 = ldsH + T1_H + (rr & 1) * T1_BUF;
        #pragma unroll
        for (int ct = 0; ct < 3; ++ct) {
            // bf[n=j][k=m2]: B1 native is [r][k][j] -> 8 j-coalesced strided
            // dwords (4 x 64B segments per instr); k>=24 pad -> quad 3 zeroed.
            half8_t bf;
            #pragma unroll
            for (int z = 0; z < 8; ++z) bf[z] = (_Float16)0.f;
            if (quad < 3) {
                const float* p = B1 + ((size_t)rr * M2_ + quad * 8) * N2_ + ct * 16 + l16;
                #pragma unroll
                for (int kk = 0; kk < 8; ++kk)
                    bf[kk] = (_Float16)(p[kk * N2_] * 64.0f);
            }
            f32x4_t c = __builtin_amdgcn_mfma_f32_16x16x32_f16(xp_frag, bf, zero4, 0, 0, 0);
            half4_t pk;
            pk[0] = (_Float16)c[0]; pk[1] = (_Float16)c[1];
            pk[2] = (_Float16)c[2]; pk[3] = (_Float16)c[3];
            const int s = s1_t * 48 + ct * 16 + l16;        // (t,j) row of T1T
            *(half4_t*)&t1[s * 40 + s1_i0] = pk;            // 4 consecutive i
        }
    };

    auto stage2 = [&](int rr) {   // hacc += (A1_r*64) * T1_r
        const _Float16* t1 = ldsH + T1_H + (rr & 1) * T1_BUF;
        // af[n1][k=i]: A1 native [r][n1][i] is i-contiguous -> 2 dwordx4 + cvt
        const half8_t af = cvt8c(A1 + ((size_t)rr * N1_ + (w & 3) * 16 + l16) * M1_ + quad * 8);
        #pragma unroll
        for (int u = 0; u < 6; ++u) {
            const int ct = (w >> 2) + 2 * u;
            const half8_t bf = *(const half8_t*)&t1[(ct * 16 + l16) * 40 + quad * 8];
            hacc[u] = __builtin_amdgcn_mfma_f32_16x16x32_f16(af, bf, hacc[u], 0, 0, 0);
        }
    };

    // ---------------- phase A: 1 barrier per r, T1 double-buffered -----------
    stage1(0);
    __syncthreads();
    for (int r = 0; r < R_; ++r) {
        stage2(r);
        if (r + 1 < R_) stage1(r + 1);
        __syncthreads();
    }

    // ---------------- epilogue 1: h = hacc/4096 + b1; Hg = gelu(h)*4096 ------
    {
        const float inv4096 = 1.0f / 4096.0f;
        #pragma unroll
        for (int u = 0; u < 6; ++u) {
            const int ct = (w >> 2) + 2 * u;
            const int s  = ct * 16 + l16;           // (t,n2)
            const int n2 = s % 48;
            const int n1b = (w & 3) * 16 + quad * 4;
            half4_t p;
            #pragma unroll
            for (int rg = 0; rg < 4; ++rg) {
                const float hv = hacc[u][rg] * inv4096 + b1[(n1b + rg) * 48 + n2];
                float g;
                if (__builtin_expect(fabsf(hv) < 0.04f, 1)) {
                    g = fmaf(0.3989422804f * hv, hv, 0.5f * hv);  // |err| = O(h^4)
                } else {
                    g = 0.5f * hv * (1.0f + erff(hv * 0.70710678118654752f));
                }
                p[rg] = (_Float16)(g * 4096.0f);
            }
            *(half4_t*)&ldsH[HG_H + s * 72 + n1b] = p;   // HgT[(t,n2)][n1]
        }
    }

    // ---------------- hoisted phase-B weight fragments (register-resident) ---
    const int kh  = w >> 2;        // stage-4 k-half (r 0..3 | 4..7)
    const int rt4 = (w >> 1) & 1;  // stage-4 m1 tile
    const int ct4 = w & 1;         // stage-4 m2 tile

    // stage-3 af: A2 native [r][m1][n1] is n1-contiguous; wave w owns r=w.
    half8_t w3f[2][2];
    #pragma unroll
    for (int e = 0; e < 2; ++e)
        #pragma unroll
        for (int kk = 0; kk < 2; ++kk)
            w3f[e][kk] = cvt8c(A2 + ((size_t)w * M1_ + e * 16 + l16) * N1_ + kk * 32 + quad * 8);

    // stage-4 bf[m2][k=r*48+n2]: B2 native [r][n2][m2] -> strided dwords,
    // m2-coalesced across lanes; m2>=24 lanes zeroed (pad columns, discarded).
    half8_t w4f[6];
    {
        const int m2c = ct4 * 16 + l16;
        #pragma unroll
        for (int kk = 0; kk < 6; ++kk) {
            #pragma unroll
            for (int z = 0; z < 8; ++z) w4f[kk][z] = (_Float16)0.f;
            if (m2c < M2_) {
                const float* p = B2 + ((size_t)kh * 192 + kk * 32 + quad * 8) * M2_ + m2c;
                #pragma unroll
                for (int j2 = 0; j2 < 8; ++j2)
                    w4f[kk][j2] = (_Float16)(p[j2 * M2_] * 64.0f);
            }
        }
    }
    __syncthreads();

    // ---------------- phase B per token: Z'=(A2*64)*Hg'; out=Z'*B2'; store ---
    const float sc = 1.0f / 16777216.0f;   // 2^-24
    for (int tt = 0; tt < T_TOK; ++tt) {
        // stage 3: wave w owns r=w rows of Z'. 6 tiles x K=64. Last read of
        // HG quarter tt.
        f32x4_t zc[6];
        #pragma unroll
        for (int u = 0; u < 6; ++u) zc[u] = zero4;
        #pragma unroll
        for (int e = 0; e < 2; ++e)
            #pragma unroll
            for (int ct = 0; ct < 3; ++ct) {
                const int u = e * 3 + ct;
                #pragma unroll
                for (int kk = 0; kk < 2; ++kk) {
                    const half8_t bf = *(const half8_t*)&ldsH[HG_H + (tt * 48 + ct * 16 + l16) * 72 + kk * 32 + quad * 8];
                    zc[u] = __builtin_amdgcn_mfma_f32_16x16x32_f16(w3f[e][kk], bf, zc[u], 0, 0, 0);
                }
            }
        // scatter C -> A-layout Z'[m1][r*48+n2] (f16 writes; 2-way max)
        #pragma unroll
        for (int e = 0; e < 2; ++e)
            #pragma unroll
            for (int ct = 0; ct < 3; ++ct) {
                const int u = e * 3 + ct;
                const int kcol = w * 48 + ct * 16 + l16;
                #pragma unroll
                for (int rg = 0; rg < 4; ++rg)
                    ldsH[ZP_H + (16 * e + quad * 4 + rg) * 392 + kcol] = (_Float16)(zc[u][rg]);
            }
        __syncthreads();   // scatter visible; also: all stage-3 reads of HG quarter tt done

        // stage 4: oc = Z' * B2' (K-half = 192 per wave; kh in {0,1})
        f32x4_t oc = zero4;
        #pragma unroll
        for (int kk = 0; kk < 6; ++kk) {
            const int k0 = kh * 192 + kk * 32;
            const half8_t af = *(const half8_t*)&ldsH[ZP_H + (rt4 * 16 + l16) * 392 + k0 + quad * 8];
            oc = __builtin_amdgcn_mfma_f32_16x16x32_f16(af, w4f[kk], oc, 0, 0, 0);
        }
        // partials -> dead HG quarter tt, as f32 [768][2] (6144 B <= 6912 B)
        float* outT = ldsF + 1728 * tt;    // byte offset 6912*tt
        const int m2c = ct4 * 16 + l16;
        if (m2c < M2_) {
            #pragma unroll
            for (int rg = 0; rg < 4; ++rg) {
                const int m1 = rt4 * 16 + quad * 4 + rg;
                outT[(m1 * M2_ + m2c) * 2 + kh] = oc[rg];
            }
        }
        __syncthreads();   // partials visible; ZP free for next tt's scatter

        // per-token final: sum kh halves, *2^-24, +b2, q-gather, coalesced store
        {
            float* orow = out + (size_t)(tokBase + tt) * DIN;
            const int j0 = tid;                       // 0..511
            const int qa = idx64 ? q[2 * j0] : q[j0];
            orow[j0] = (outT[qa * 2] + outT[qa * 2 + 1]) * sc + b2[qa];
            if (tid < DIN - 512) {                    // 256 threads cover 512..767
                const int j1 = 512 + tid;
                const int qb = idx64 ? q[2 * j1] : q[j1];
                orow[j1] = (outT[qb * 2] + outT[qb * 2 + 1]) * sc + b2[qb];
            }
        }
        // no extra barrier: next stage-3 touches HG quarters > tt and ZP only;
        // ZP reads (stage 4) completed before the barrier above.
    }
}

} // namespace

extern "C" void kernel_launch(void* const* d_in, const int* in_sizes, int n_in,
                              void* d_out, int out_size, void* d_ws, size_t ws_size,
                              hipStream_t stream) {
    const float* x   = (const float*)d_in[0];
    const float* A1  = (const float*)d_in[1];
    const float* B1  = (const float*)d_in[2];
    const float* A2  = (const float*)d_in[3];
    const float* B2  = (const float*)d_in[4];
    const float* b1  = (const float*)d_in[5];
    const float* b2  = (const float*)d_in[6];
    const int*   piv = (const int*)d_in[7];
    const int*   q   = (const int*)d_in[8];
    float* out = (float*)d_out;

    const int tokens = in_sizes[0] / DIN;          // 4096
    const int grid   = tokens / T_TOK;             // 1024

    (void)hipFuncSetAttribute((const void*)kn_mfma,
                              hipFuncAttributeMaxDynamicSharedMemorySize,
                              LDS_BYTES);
    kn_mfma<<<grid, NTHREADS, LDS_BYTES, stream>>>(x, A1, B1, A2, B2, b1, b2, piv, q, out);
}

// Round 7
// 117.132 us; speedup vs baseline: 1.4209x; 1.1765x over previous
//
#include <hip/hip_runtime.h>
#include <cmath>

namespace {

typedef _Float16 half8_t __attribute__((ext_vector_type(8)));
typedef _Float16 half4_t __attribute__((ext_vector_type(4)));
typedef float    f32x4_t __attribute__((ext_vector_type(4)));

constexpr int R_ = 8, M1_ = 32, N1_ = 64, M2_ = 24, N2_ = 48;
constexpr int DIN = 768;          // M1*M2
constexpr int T_TOK = 8;          // tokens per workgroup -> grid 512 = 2 x 256 CUs
constexpr int NTHREADS = 512;     // 8 waves

// ---- d_ws f16 weights (element offsets), all *64 (2^6, exact), MFMA
// fragment-native (rows = operand rows, k contiguous, 16B-aligned).
constexpr int W1_OFF = 0;         // [r][j=48][k=40]  = B1[r][k][j]; k>=24 -> 0
constexpr int W2_OFF = 30720;     // [n1=64][r*32+i]  = A1[r][n1][i]
constexpr int W3_OFF = 47104;     // [r*32+m1][n1=64] = A2 flat
constexpr int W4_OFF = 63488;     // [m2=32][r*48+n2] = B2[r][n2][m2]; m2>=24 -> 0
constexpr int W_TOTAL = 75776;    // 151552 B in d_ws

// ---- LDS (f16 element offsets), 80384 B -> 2 blocks/CU, grid fully resident.
// Phase A: T1A + T1B dbuf; XP overlays T1B (XP dead after xp_frag reg loads;
// T1B first written one barrier after all waves' frag loads -> safe).
// Phase B: HG + ZP overlay phase A after the final phase-A barrier.
// Per-token stage-4 partials reuse that token's dead HG slab (6912 B >= 6144).
constexpr int T1A_H = 0;          // [384][40]
constexpr int T1B_H = 15360;      // [384][40]
constexpr int XP_H  = 15360;      // [256][40] (inside T1B)
constexpr int HG_H  = 0;          // [384][72]
constexpr int ZP_H  = 27648;      // [32][392]
constexpr int LDS_BYTES = (27648 + 12544) * 2;   // 80384

__global__ void prep_weights(const float* __restrict__ A1, const float* __restrict__ B1,
                             const float* __restrict__ A2, const float* __restrict__ B2,
                             _Float16* __restrict__ W)
{
    const int idx = blockIdx.x * 256 + threadIdx.x;
    if (idx >= W_TOTAL) return;
    float v;
    if (idx < W2_OFF) {                       // W1[r][j][k] = B1[r][k][j]
        int k = idx % 40, j = (idx / 40) % 48, r = idx / 1920;
        v = (k < 24) ? B1[(r * 24 + k) * 48 + j] : 0.0f;
    } else if (idx < W3_OFF) {                // W2[n1][r*32+i] = A1[r][n1][i]
        int t = idx - W2_OFF;
        int rk = t & 255, n1 = t >> 8;
        v = A1[((rk >> 5) * 64 + n1) * 32 + (rk & 31)];
    } else if (idx < W4_OFF) {                // W3 = A2 flat
        v = A2[idx - W3_OFF];
    } else {                                  // W4[m2][r*48+n2] = B2[r][n2][m2]
        int t = idx - W4_OFF;
        int k = t % 384, m2 = t / 384;
        v = (m2 < 24) ? B2[k * 24 + m2] : 0.0f;
    }
    W[idx] = (_Float16)(v * 64.0f);
}

__global__ __launch_bounds__(NTHREADS, 4)
void kn_mfma(const float* __restrict__ x,
             const float* __restrict__ b1,
             const float* __restrict__ b2,
             const int* __restrict__ p_inv,
             const int* __restrict__ q,
             const _Float16* __restrict__ W,
             float* __restrict__ out)
{
    extern __shared__ char smem[];
    _Float16* ldsH = (_Float16*)smem;
    float*    ldsF = (float*)smem;

    const int tid  = threadIdx.x;
    const int lane = tid & 63;
    const int w    = __builtin_amdgcn_readfirstlane(tid >> 6);  // uniform wave id
    const int quad = lane >> 4;
    const int l16  = lane & 15;

    const long tokBase = (long)blockIdx.x * T_TOK;
    // p_inv/q may be int64 or int32; a permutation can't have two zeros.
    const bool idx64 = (p_inv[1] == 0 && p_inv[3] == 0);

    // ---------------- fill XP[(t*32+i)][m2] = f16(x[t][p_inv[i*24+m2]]) ------
    {
        const int t = w;                        // wave fills its own token
        const float* xrow = x + (size_t)(tokBase + t) * DIN;
        #pragma unroll
        for (int c = 0; c < 12; ++c) {
            const int kIdx = c * 64 + lane;
            const int pidx = idx64 ? p_inv[2 * kIdx] : p_inv[kIdx];
            const int i = kIdx / 24, m2 = kIdx - i * 24;
            ldsH[XP_H + (t * 32 + i) * 40 + m2] = (_Float16)xrow[pidx];
        }
        // zero k-pad cols [24,40): 256 rows x 16 cols, one b128 per thread
        const int r0 = tid >> 1, c0 = 24 + (tid & 1) * 8;
        *(half8_t*)&ldsH[XP_H + r0 * 40 + c0] = half8_t{0, 0, 0, 0, 0, 0, 0, 0};
    }
    __syncthreads();

    const f32x4_t zero4 = {0.f, 0.f, 0.f, 0.f};

    // stage-1 A fragments (r-invariant): wave w owns token w's 32 (t,i)-rows.
    const half8_t xp0 = *(const half8_t*)&ldsH[XP_H + (32 * w + l16) * 40 + quad * 8];
    const half8_t xp1 = *(const half8_t*)&ldsH[XP_H + (32 * w + 16 + l16) * 40 + quad * 8];

    // stage-2 accumulators: h*2^12; wave: n1-tile w&3, (t,n2)-tiles (w>>2)+2u
    f32x4_t hacc[12];
    #pragma unroll
    for (int u = 0; u < 12; ++u) hacc[u] = zero4;

    auto stage1 = [&](int rr) {   // T1T[(t*48+j)][i] = (XP * B1_r*64), f16
        _Float16* t1 = ldsH + ((rr & 1) ? T1B_H : T1A_H);
        #pragma unroll
        for (int ct = 0; ct < 3; ++ct) {
            const half8_t bf = *(const half8_t*)&W[W1_OFF + (rr * 48 + ct * 16 + l16) * 40 + quad * 8];
            const f32x4_t c0 = __builtin_amdgcn_mfma_f32_16x16x32_f16(xp0, bf, zero4, 0, 0, 0);
            const f32x4_t c1 = __builtin_amdgcn_mfma_f32_16x16x32_f16(xp1, bf, zero4, 0, 0, 0);
            const int s = w * 48 + ct * 16 + l16;   // (t=w, j) row of T1T
            half4_t p;
            p[0] = (_Float16)c0[0]; p[1] = (_Float16)c0[1];
            p[2] = (_Float16)c0[2]; p[3] = (_Float16)c0[3];
            *(half4_t*)&t1[s * 40 + quad * 4] = p;
            p[0] = (_Float16)c1[0]; p[1] = (_Float16)c1[1];
            p[2] = (_Float16)c1[2]; p[3] = (_Float16)c1[3];
            *(half4_t*)&t1[s * 40 + 16 + quad * 4] = p;
        }
    };

    auto stage2 = [&](int rr) {   // hacc += (A1_r*64) * T1_r
        const _Float16* t1 = ldsH + ((rr & 1) ? T1B_H : T1A_H);
        const half8_t af = *(const half8_t*)&W[W2_OFF + ((w & 3) * 16 + l16) * 256 + rr * 32 + quad * 8];
        #pragma unroll
        for (int u = 0; u < 12; ++u) {
            const int ct = (w >> 2) + 2 * u;
            const half8_t bf = *(const half8_t*)&t1[(ct * 16 + l16) * 40 + quad * 8];
            hacc[u] = __builtin_amdgcn_mfma_f32_16x16x32_f16(af, bf, hacc[u], 0, 0, 0);
        }
    };

    // ---------------- phase A: 1 barrier per r, T1 double-buffered -----------
    stage1(0);
    __syncthreads();
    for (int r = 0; r < R_; ++r) {
        stage2(r);
        if (r + 1 < R_) stage1(r + 1);
        __syncthreads();
    }

    // ---------------- epilogue: h = hacc/4096 + b1; HgT = gelu(h)*4096 -------
    {
        const float inv4096 = 1.0f / 4096.0f;
        #pragma unroll
        for (int u = 0; u < 12; ++u) {
            const int ct = (w >> 2) + 2 * u;
            const int s  = ct * 16 + l16;           // (t,n2) in [0,384)
            const int n2 = s % 48;
            const int n1b = (w & 3) * 16 + quad * 4;
            half4_t p;
            #pragma unroll
            for (int rg = 0; rg < 4; ++rg) {
                const float hv = hacc[u][rg] * inv4096 + b1[(n1b + rg) * 48 + n2];
                float g;
                if (__builtin_expect(fabsf(hv) < 0.04f, 1)) {
                    g = fmaf(0.3989422804f * hv, hv, 0.5f * hv);  // |err| = O(h^4)
                } else {
                    g = 0.5f * hv * (1.0f + erff(hv * 0.70710678118654752f));
                }
                p[rg] = (_Float16)(g * 4096.0f);
            }
            *(half4_t*)&ldsH[HG_H + s * 72 + n1b] = p;   // HgT[(t,n2)][n1]
        }
    }
    __syncthreads();

    // ---------------- phase B per token: Z'=(A2*64)*Hg'; out = Z'*B2' --------
    const int kh  = w >> 2;        // stage-4 k-half (r 0..3 | 4..7)
    const int rt4 = (w >> 1) & 1;  // stage-4 m1 tile
    const int ct4 = w & 1;         // stage-4 m2 tile
    const float sc = 1.0f / 16777216.0f;   // 2^-24

    for (int tt = 0; tt < T_TOK; ++tt) {
        // stage 3: wave w owns r=w rows of Z'. 6 tiles x K=64. Last read of
        // HG slab tt.
        f32x4_t zc[6];
        #pragma unroll
        for (int u = 0; u < 6; ++u) zc[u] = zero4;
        #pragma unroll
        for (int e = 0; e < 2; ++e)
            #pragma unroll
            for (int ct = 0; ct < 3; ++ct) {
                const int u = e * 3 + ct;
                #pragma unroll
                for (int kk = 0; kk < 2; ++kk) {
                    const half8_t af = *(const half8_t*)&W[W3_OFF + (w * 32 + e * 16 + l16) * 64 + kk * 32 + quad * 8];
                    const half8_t bf = *(const half8_t*)&ldsH[HG_H + (tt * 48 + ct * 16 + l16) * 72 + kk * 32 + quad * 8];
                    zc[u] = __builtin_amdgcn_mfma_f32_16x16x32_f16(af, bf, zc[u], 0, 0, 0);
                }
            }
        // scatter C -> A-layout Z'[m1][r*48+n2]
        #pragma unroll
        for (int e = 0; e < 2; ++e)
            #pragma unroll
            for (int ct = 0; ct < 3; ++ct) {
                const int u = e * 3 + ct;
                const int kcol = w * 48 + ct * 16 + l16;
                #pragma unroll
                for (int rg = 0; rg < 4; ++rg)
                    ldsH[ZP_H + (16 * e + quad * 4 + rg) * 392 + kcol] = (_Float16)(zc[u][rg]);
            }
        __syncthreads();   // scatter visible; all stage-3 reads of HG slab tt done

        // stage 4: oc = Z' * B2' (K-half = 192 per wave)
        f32x4_t oc = zero4;
        #pragma unroll
        for (int kk = 0; kk < 6; ++kk) {
            const int k0 = kh * 192 + kk * 32;
            const half8_t af = *(const half8_t*)&ldsH[ZP_H + (rt4 * 16 + l16) * 392 + k0 + quad * 8];
            const half8_t bf = *(const half8_t*)&W[W4_OFF + (ct4 * 16 + l16) * 384 + k0 + quad * 8];
            oc = __builtin_amdgcn_mfma_f32_16x16x32_f16(af, bf, oc, 0, 0, 0);
        }
        // partials -> dead HG slab tt, f32 [768][2] (6144 B <= 6912 B)
        float* outT = ldsF + 1728 * tt;
        const int m2c = ct4 * 16 + l16;
        if (m2c < M2_) {
            #pragma unroll
            for (int rg = 0; rg < 4; ++rg) {
                const int m1 = rt4 * 16 + quad * 4 + rg;
                outT[(m1 * M2_ + m2c) * 2 + kh] = oc[rg];
            }
        }
        __syncthreads();   // partials visible; ZP free for next tt

        // per-token final: sum halves, *2^-24, +b2, q-gather, coalesced store
        {
            float* orow = out + (size_t)(tokBase + tt) * DIN;
            const int qa = idx64 ? q[2 * tid] : q[tid];
            orow[tid] = (outT[qa * 2] + outT[qa * 2 + 1]) * sc + b2[qa];
            if (tid < DIN - 512) {
                const int j1 = 512 + tid;
                const int qb = idx64 ? q[2 * j1] : q[j1];
                orow[j1] = (outT[qb * 2] + outT[qb * 2 + 1]) * sc + b2[qb];
            }
        }
        // next stage-3 touches HG slabs > tt and ZP only; safe without barrier
    }
}

} // namespace

extern "C" void kernel_launch(void* const* d_in, const int* in_sizes, int n_in,
                              void* d_out, int out_size, void* d_ws, size_t ws_size,
                              hipStream_t stream) {
    const float* x   = (const float*)d_in[0];
    const float* A1  = (const float*)d_in[1];
    const float* B1  = (const float*)d_in[2];
    const float* A2  = (const float*)d_in[3];
    const float* B2  = (const float*)d_in[4];
    const float* b1  = (const float*)d_in[5];
    const float* b2  = (const float*)d_in[6];
    const int*   piv = (const int*)d_in[7];
    const int*   q   = (const int*)d_in[8];
    float* out = (float*)d_out;
    _Float16* Wws = (_Float16*)d_ws;

    const int tokens = in_sizes[0] / DIN;          // 4096
    const int grid   = tokens / T_TOK;             // 512 = 2 per CU, 1 generation

    prep_weights<<<(W_TOTAL + 255) / 256, 256, 0, stream>>>(A1, B1, A2, B2, Wws);

    (void)hipFuncSetAttribute((const void*)kn_mfma,
                              hipFuncAttributeMaxDynamicSharedMemorySize,
                              LDS_BYTES);
    kn_mfma<<<grid, NTHREADS, LDS_BYTES, stream>>>(x, b1, b2, piv, q, Wws, out);
}

// Round 8
// 111.179 us; speedup vs baseline: 1.4970x; 1.0535x over previous
//
#include <hip/hip_runtime.h>
#include <cmath>

namespace {

typedef _Float16 half8_t __attribute__((ext_vector_type(8)));
typedef _Float16 half4_t __attribute__((ext_vector_type(4)));
typedef float    f32x4_t __attribute__((ext_vector_type(4)));

constexpr int R_ = 8, M1_ = 32, N1_ = 64, M2_ = 24, N2_ = 48;
constexpr int DIN = 768;          // M1*M2
constexpr int T_TOK = 8;          // tokens per workgroup -> grid 512 = 2 x 256 CUs
constexpr int NTHREADS = 512;     // 8 waves

// ---- d_ws f16 weights (element offsets), all *64 (2^6, exact), MFMA
// fragment-native (rows = operand rows, k contiguous, 16B-aligned).
constexpr int W1_OFF = 0;         // [r][j=48][k=40]  = B1[r][k][j]; k>=24 -> 0
constexpr int W2_OFF = 30720;     // [n1=64][r*32+i]  = A1[r][n1][i]
constexpr int W3_OFF = 47104;     // [r*32+m1][n1=64] = A2 flat
constexpr int W4_OFF = 63488;     // [m2=32][r*48+n2] = B2[r][n2][m2]; m2>=24 -> 0
constexpr int W_TOTAL = 75776;    // 151552 B in d_ws

// ---- LDS (f16 element offsets), 80384 B -> 2 blocks/CU, grid fully resident.
// Phase A: T1A + T1B dbuf; XP overlays T1B (XP dead after xp_frag reg loads;
// T1B first written one barrier after all waves' frag loads -> safe).
// Phase B: HG + ZP overlay phase A after the final phase-A barrier.
// Per-token stage-4 partials P[2][768] f32 (6144 B) reuse that token's dead
// HG slab (6912 B).
constexpr int T1A_H = 0;          // [384][40]
constexpr int T1B_H = 15360;      // [384][40]
constexpr int XP_H  = 15360;      // [256][40] (inside T1B)
constexpr int HG_H  = 0;          // [384][72]
constexpr int ZP_H  = 27648;      // [32][392]
constexpr int LDS_BYTES = (27648 + 12544) * 2;   // 80384

__global__ void prep_weights(const float* __restrict__ A1, const float* __restrict__ B1,
                             const float* __restrict__ A2, const float* __restrict__ B2,
                             _Float16* __restrict__ W)
{
    const int idx = blockIdx.x * 256 + threadIdx.x;
    if (idx >= W_TOTAL) return;
    float v;
    if (idx < W2_OFF) {                       // W1[r][j][k] = B1[r][k][j]
        int k = idx % 40, j = (idx / 40) % 48, r = idx / 1920;
        v = (k < 24) ? B1[(r * 24 + k) * 48 + j] : 0.0f;
    } else if (idx < W3_OFF) {                // W2[n1][r*32+i] = A1[r][n1][i]
        int t = idx - W2_OFF;
        int rk = t & 255, n1 = t >> 8;
        v = A1[((rk >> 5) * 64 + n1) * 32 + (rk & 31)];
    } else if (idx < W4_OFF) {                // W3 = A2 flat
        v = A2[idx - W3_OFF];
    } else {                                  // W4[m2][r*48+n2] = B2[r][n2][m2]
        int t = idx - W4_OFF;
        int k = t % 384, m2 = t / 384;
        v = (m2 < 24) ? B2[k * 24 + m2] : 0.0f;
    }
    W[idx] = (_Float16)(v * 64.0f);
}

__global__ __launch_bounds__(NTHREADS, 4)
void kn_mfma(const float* __restrict__ x,
             const float* __restrict__ b1,
             const float* __restrict__ b2,
             const int* __restrict__ p_inv,
             const int* __restrict__ q,
             const _Float16* __restrict__ W,
             float* __restrict__ out)
{
    extern __shared__ char smem[];
    _Float16* ldsH = (_Float16*)smem;
    float*    ldsF = (float*)smem;

    const int tid  = threadIdx.x;
    const int lane = tid & 63;
    const int w    = __builtin_amdgcn_readfirstlane(tid >> 6);  // uniform wave id
    const int quad = lane >> 4;
    const int l16  = lane & 15;

    const long tokBase = (long)blockIdx.x * T_TOK;
    // p_inv/q may be int64 or int32; a permutation can't have two zeros.
    const bool idx64 = (p_inv[1] == 0 && p_inv[3] == 0);

    // ---------------- fill XP[(t*32+i)][m2] = f16(x[t][p_inv[i*24+m2]]) ------
    {
        const int t = w;                        // wave fills its own token
        const float* xrow = x + (size_t)(tokBase + t) * DIN;
        #pragma unroll
        for (int c = 0; c < 12; ++c) {
            const int kIdx = c * 64 + lane;
            const int pidx = idx64 ? p_inv[2 * kIdx] : p_inv[kIdx];
            const int i = kIdx / 24, m2 = kIdx - i * 24;
            ldsH[XP_H + (t * 32 + i) * 40 + m2] = (_Float16)xrow[pidx];
        }
        // zero k-pad cols [24,40): 256 rows x 16 cols, one b128 per thread
        const int r0 = tid >> 1, c0 = 24 + (tid & 1) * 8;
        *(half8_t*)&ldsH[XP_H + r0 * 40 + c0] = half8_t{0, 0, 0, 0, 0, 0, 0, 0};
    }
    __syncthreads();

    const f32x4_t zero4 = {0.f, 0.f, 0.f, 0.f};

    // stage-1 A fragments (r-invariant): wave w owns token w's 32 (t,i)-rows.
    const half8_t xp0 = *(const half8_t*)&ldsH[XP_H + (32 * w + l16) * 40 + quad * 8];
    const half8_t xp1 = *(const half8_t*)&ldsH[XP_H + (32 * w + 16 + l16) * 40 + quad * 8];

    // stage-2 accumulators: h*2^12; wave: n1-tile w&3, (t,n2)-tiles (w>>2)+2u
    f32x4_t hacc[12];
    #pragma unroll
    for (int u = 0; u < 12; ++u) hacc[u] = zero4;

    auto stage1 = [&](int rr) {   // T1T[(t*48+j)][i] = (XP * B1_r*64), f16
        _Float16* t1 = ldsH + ((rr & 1) ? T1B_H : T1A_H);
        #pragma unroll
        for (int ct = 0; ct < 3; ++ct) {
            const half8_t bf = *(const half8_t*)&W[W1_OFF + (rr * 48 + ct * 16 + l16) * 40 + quad * 8];
            const f32x4_t c0 = __builtin_amdgcn_mfma_f32_16x16x32_f16(xp0, bf, zero4, 0, 0, 0);
            const f32x4_t c1 = __builtin_amdgcn_mfma_f32_16x16x32_f16(xp1, bf, zero4, 0, 0, 0);
            const int s = w * 48 + ct * 16 + l16;   // (t=w, j) row of T1T
            half4_t p;
            p[0] = (_Float16)c0[0]; p[1] = (_Float16)c0[1];
            p[2] = (_Float16)c0[2]; p[3] = (_Float16)c0[3];
            *(half4_t*)&t1[s * 40 + quad * 4] = p;
            p[0] = (_Float16)c1[0]; p[1] = (_Float16)c1[1];
            p[2] = (_Float16)c1[2]; p[3] = (_Float16)c1[3];
            *(half4_t*)&t1[s * 40 + 16 + quad * 4] = p;
        }
    };

    auto stage2 = [&](int rr) {   // hacc += (A1_r*64) * T1_r
        const _Float16* t1 = ldsH + ((rr & 1) ? T1B_H : T1A_H);
        const half8_t af = *(const half8_t*)&W[W2_OFF + ((w & 3) * 16 + l16) * 256 + rr * 32 + quad * 8];
        #pragma unroll
        for (int u = 0; u < 12; ++u) {
            const int ct = (w >> 2) + 2 * u;
            const half8_t bf = *(const half8_t*)&t1[(ct * 16 + l16) * 40 + quad * 8];
            hacc[u] = __builtin_amdgcn_mfma_f32_16x16x32_f16(af, bf, hacc[u], 0, 0, 0);
        }
    };

    // ---------------- phase A: 1 barrier per r, T1 double-buffered -----------
    stage1(0);
    __syncthreads();
    for (int r = 0; r < R_; ++r) {
        stage2(r);
        if (r + 1 < R_) stage1(r + 1);
        __syncthreads();
    }

    // ---------------- epilogue: h = hacc/4096 + b1; HgT = gelu(h)*4096 -------
    {
        const float inv4096 = 1.0f / 4096.0f;
        #pragma unroll
        for (int u = 0; u < 12; ++u) {
            const int ct = (w >> 2) + 2 * u;
            const int s  = ct * 16 + l16;           // (t,n2) in [0,384)
            const int n2 = s % 48;
            const int n1b = (w & 3) * 16 + quad * 4;
            half4_t p;
            #pragma unroll
            for (int rg = 0; rg < 4; ++rg) {
                const float hv = hacc[u][rg] * inv4096 + b1[(n1b + rg) * 48 + n2];
                float g;
                if (__builtin_expect(fabsf(hv) < 0.04f, 1)) {
                    g = fmaf(0.3989422804f * hv, hv, 0.5f * hv);  // |err| = O(h^4)
                } else {
                    g = 0.5f * hv * (1.0f + erff(hv * 0.70710678118654752f));
                }
                p[rg] = (_Float16)(g * 4096.0f);
            }
            *(half4_t*)&ldsH[HG_H + s * 72 + n1b] = p;   // HgT[(t,n2)][n1]
        }
    }

    // ---------------- phase-B hoists (token-invariant, register-resident) ----
    const int kh  = w >> 2;        // stage-4 k-half (r 0..3 | 4..7)
    const int rt4 = (w >> 1) & 1;  // stage-4 m1 tile
    const int ct4 = w & 1;         // stage-4 m2 tile
    const float sc = 1.0f / 16777216.0f;   // 2^-24

    // stage-3 B-operand (A2 rows = m1); wave w owns r=w
    half8_t w3f[2][2];
    #pragma unroll
    for (int e = 0; e < 2; ++e)
        #pragma unroll
        for (int kk = 0; kk < 2; ++kk)
            w3f[e][kk] = *(const half8_t*)&W[W3_OFF + (w * 32 + e * 16 + l16) * 64 + kk * 32 + quad * 8];

    // stage-4 A-operand (B2 rows = m2), K-half kh
    half8_t w4f[6];
    #pragma unroll
    for (int kk = 0; kk < 6; ++kk)
        w4f[kk] = *(const half8_t*)&W[W4_OFF + (ct4 * 16 + l16) * 384 + kh * 192 + kk * 32 + quad * 8];

    // final-store q/b2 (token-invariant)
    const int  qa = idx64 ? q[2 * tid] : q[tid];
    const float ba = b2[qa];
    const bool has2 = tid < DIN - 512;
    int qb = 0; float bb = 0.f;
    if (has2) {
        qb = idx64 ? q[2 * (512 + tid)] : q[512 + tid];
        bb = b2[qb];
    }
    __syncthreads();

    // ---------------- phase B per token ---------------------------------------
    // stage 3 (swapped): D[(t,n2)][m1] = Hg' x (A2*64): lane holds 4 consecutive
    // n2 at fixed m1 -> one b64 scatter per tile into Z'[m1][r*48+n2].
    // stage 4 (swapped): D[m2][m1] = (B2'*64) x Z': lane holds 4 consecutive m2
    // at fixed m1 -> one masked b128 write into P[kh][m1*24+m2].
    for (int tt = 0; tt < T_TOK; ++tt) {
        f32x4_t zc[6];
        #pragma unroll
        for (int u = 0; u < 6; ++u) zc[u] = zero4;
        #pragma unroll
        for (int ct = 0; ct < 3; ++ct)
            #pragma unroll
            for (int kk = 0; kk < 2; ++kk) {
                const half8_t af = *(const half8_t*)&ldsH[HG_H + (tt * 48 + ct * 16 + l16) * 72 + kk * 32 + quad * 8];
                #pragma unroll
                for (int e = 0; e < 2; ++e) {
                    const int u = ct * 2 + e;
                    zc[u] = __builtin_amdgcn_mfma_f32_16x16x32_f16(af, w3f[e][kk], zc[u], 0, 0, 0);
                }
            }
        // scatter: Z'[m1 = e*16+l16][w*48 + ct*16 + quad*4 + rg], b64 each
        #pragma unroll
        for (int ct = 0; ct < 3; ++ct)
            #pragma unroll
            for (int e = 0; e < 2; ++e) {
                const int u = ct * 2 + e;
                half4_t p;
                p[0] = (_Float16)zc[u][0]; p[1] = (_Float16)zc[u][1];
                p[2] = (_Float16)zc[u][2]; p[3] = (_Float16)zc[u][3];
                *(half4_t*)&ldsH[ZP_H + (e * 16 + l16) * 392 + w * 48 + ct * 16 + quad * 4] = p;
            }
        __syncthreads();   // scatter visible; all stage-3 reads of HG slab tt done

        // stage 4: oc = (B2'*64) x Z'  (K-half = 192 per wave)
        f32x4_t oc = zero4;
        #pragma unroll
        for (int kk = 0; kk < 6; ++kk) {
            const half8_t zf = *(const half8_t*)&ldsH[ZP_H + (rt4 * 16 + l16) * 392 + kh * 192 + kk * 32 + quad * 8];
            oc = __builtin_amdgcn_mfma_f32_16x16x32_f16(w4f[kk], zf, oc, 0, 0, 0);
        }
        // P[kh][m1*24+m2], contiguous 4 m2 -> b128; slab tt (1728 f32)
        {
            const int m2b = ct4 * 16 + quad * 4;
            if (m2b < M2_) {
                *(f32x4_t*)&ldsF[1728 * tt + kh * 768 + (rt4 * 16 + l16) * 24 + m2b] = oc;
            }
        }
        __syncthreads();   // partials visible; ZP free for next tt

        // per-token final: sum halves, *2^-24, +b2, q-gather, coalesced store
        {
            const float* Pb = ldsF + 1728 * tt;
            float* orow = out + (size_t)(tokBase + tt) * DIN;
            orow[tid] = (Pb[qa] + Pb[768 + qa]) * sc + ba;
            if (has2)
                orow[512 + tid] = (Pb[qb] + Pb[768 + qb]) * sc + bb;
        }
        // next stage-3 touches HG slabs > tt and ZP only; safe without barrier
    }
}

} // namespace

extern "C" void kernel_launch(void* const* d_in, const int* in_sizes, int n_in,
                              void* d_out, int out_size, void* d_ws, size_t ws_size,
                              hipStream_t stream) {
    const float* x   = (const float*)d_in[0];
    const float* A1  = (const float*)d_in[1];
    const float* B1  = (const float*)d_in[2];
    const float* A2  = (const float*)d_in[3];
    const float* B2  = (const float*)d_in[4];
    const float* b1  = (const float*)d_in[5];
    const float* b2  = (const float*)d_in[6];
    const int*   piv = (const int*)d_in[7];
    const int*   q   = (const int*)d_in[8];
    float* out = (float*)d_out;
    _Float16* Wws = (_Float16*)d_ws;

    const int tokens = in_sizes[0] / DIN;          // 4096
    const int grid   = tokens / T_TOK;             // 512 = 2 per CU, 1 generation

    prep_weights<<<(W_TOTAL + 255) / 256, 256, 0, stream>>>(A1, B1, A2, B2, Wws);

    (void)hipFuncSetAttribute((const void*)kn_mfma,
                              hipFuncAttributeMaxDynamicSharedMemorySize,
                              LDS_BYTES);
    kn_mfma<<<grid, NTHREADS, LDS_BYTES, stream>>>(x, b1, b2, piv, q, Wws, out);
}

// Round 9
// 110.076 us; speedup vs baseline: 1.5120x; 1.0100x over previous
//
#include <hip/hip_runtime.h>
#include <cmath>

namespace {

typedef _Float16 half8_t __attribute__((ext_vector_type(8)));
typedef _Float16 half4_t __attribute__((ext_vector_type(4)));
typedef float    f32x4_t __attribute__((ext_vector_type(4)));

constexpr int R_ = 8, M1_ = 32, N1_ = 64, M2_ = 24, N2_ = 48;
constexpr int DIN = 768;          // M1*M2
constexpr int T_TOK = 8;          // tokens per workgroup -> grid 512 = 2 x 256 CUs
constexpr int NTHREADS = 512;     // 8 waves

// ---- d_ws f16 weights (element offsets), all *64 (2^6, exact), MFMA
// fragment-native (rows = operand rows, k contiguous, 16B-aligned).
constexpr int W1_OFF = 0;         // [r][j=48][k=40]  = B1[r][k][j]; k>=24 -> 0
constexpr int W2_OFF = 30720;     // [n1=64][r*32+i]  = A1[r][n1][i]
constexpr int W3_OFF = 47104;     // [r*32+m1][n1=64] = A2 flat
constexpr int W4_OFF = 63488;     // [m2=32][r*48+n2] = B2[r][n2][m2]; m2>=24 -> 0
constexpr int W_TOTAL = 75776;    // 151552 B in d_ws

// ---- LDS (f16 element offsets), 80384 B -> 2 blocks/CU, grid fully resident.
// Phase A: T1A + T1B dbuf; XP overlays T1B (XP dead after xp_frag reg loads;
// T1B first written one barrier after all waves' frag loads -> safe).
// Phase B: HG + ZP overlay phase A after the final phase-A barrier.
// Per-token stage-4 partials P[2][768] f32 (6144 B) reuse that token's dead
// HG slab (6912 B).
constexpr int T1A_H = 0;          // [384][40]
constexpr int T1B_H = 15360;      // [384][40]
constexpr int XP_H  = 15360;      // [256][40] (inside T1B)
constexpr int HG_H  = 0;          // [384][72]
constexpr int ZP_H  = 27648;      // [32][392]
constexpr int LDS_BYTES = (27648 + 12544) * 2;   // 80384

__global__ void prep_weights(const float* __restrict__ A1, const float* __restrict__ B1,
                             const float* __restrict__ A2, const float* __restrict__ B2,
                             _Float16* __restrict__ W)
{
    const int idx = blockIdx.x * 256 + threadIdx.x;
    if (idx >= W_TOTAL) return;
    float v;
    if (idx < W2_OFF) {                       // W1[r][j][k] = B1[r][k][j]
        int k = idx % 40, j = (idx / 40) % 48, r = idx / 1920;
        v = (k < 24) ? B1[(r * 24 + k) * 48 + j] : 0.0f;
    } else if (idx < W3_OFF) {                // W2[n1][r*32+i] = A1[r][n1][i]
        int t = idx - W2_OFF;
        int rk = t & 255, n1 = t >> 8;
        v = A1[((rk >> 5) * 64 + n1) * 32 + (rk & 31)];
    } else if (idx < W4_OFF) {                // W3 = A2 flat
        v = A2[idx - W3_OFF];
    } else {                                  // W4[m2][r*48+n2] = B2[r][n2][m2]
        int t = idx - W4_OFF;
        int k = t % 384, m2 = t / 384;
        v = (m2 < 24) ? B2[k * 24 + m2] : 0.0f;
    }
    W[idx] = (_Float16)(v * 64.0f);
}

__global__ __launch_bounds__(NTHREADS, 4)
void kn_mfma(const float* __restrict__ x,
             const float* __restrict__ b1,
             const float* __restrict__ b2,
             const int* __restrict__ p_inv,
             const int* __restrict__ q,
             const _Float16* __restrict__ W,
             float* __restrict__ out)
{
    extern __shared__ char smem[];
    _Float16* ldsH = (_Float16*)smem;
    float*    ldsF = (float*)smem;

    const int tid  = threadIdx.x;
    const int lane = tid & 63;
    const int w    = __builtin_amdgcn_readfirstlane(tid >> 6);  // uniform wave id
    const int quad = lane >> 4;
    const int l16  = lane & 15;

    const long tokBase = (long)blockIdx.x * T_TOK;
    // p_inv/q may be int64 or int32; a permutation can't have two zeros.
    const bool idx64 = (p_inv[1] == 0 && p_inv[3] == 0);

    // ---------------- fill XP[(t*32+i)][m2] = f16(x[t][p_inv[i*24+m2]]) ------
    // Wave w fills AND reads only token w's 32 rows -> purely intra-wave LDS
    // dependency (lgkmcnt ordering), NO barrier needed before the frag loads.
    {
        const float* xrow = x + (size_t)(tokBase + w) * DIN;
        #pragma unroll
        for (int c = 0; c < 12; ++c) {
            const int kIdx = c * 64 + lane;
            const int pidx = idx64 ? p_inv[2 * kIdx] : p_inv[kIdx];
            const int i = kIdx / 24, m2 = kIdx - i * 24;
            ldsH[XP_H + (w * 32 + i) * 40 + m2] = (_Float16)xrow[pidx];
        }
        // zero k-pad cols [24,40) of this wave's 32 rows: lane -> (row, 8 cols)
        const int r0 = w * 32 + (lane >> 1), c0 = 24 + (lane & 1) * 8;
        *(half8_t*)&ldsH[XP_H + r0 * 40 + c0] = half8_t{0, 0, 0, 0, 0, 0, 0, 0};
    }

    const f32x4_t zero4 = {0.f, 0.f, 0.f, 0.f};

    // stage-1 A fragments (r-invariant): wave w owns token w's 32 (t,i)-rows.
    const half8_t xp0 = *(const half8_t*)&ldsH[XP_H + (32 * w + l16) * 40 + quad * 8];
    const half8_t xp1 = *(const half8_t*)&ldsH[XP_H + (32 * w + 16 + l16) * 40 + quad * 8];

    // stage-2 accumulators: h*2^12; wave: n1-tile w&3, (t,n2)-tiles (w>>2)+2u
    f32x4_t hacc[12];
    #pragma unroll
    for (int u = 0; u < 12; ++u) hacc[u] = zero4;

    // ---- rolling W-fragment prefetch (parity-indexed, fully unrolled) ------
    auto w1load = [&](int rr, int ct) -> half8_t {
        return *(const half8_t*)&W[W1_OFF + (rr * 48 + ct * 16 + l16) * 40 + quad * 8];
    };
    auto w2load = [&](int rr) -> half8_t {
        return *(const half8_t*)&W[W2_OFF + ((w & 3) * 16 + l16) * 256 + rr * 32 + quad * 8];
    };

    auto stage1 = [&](int rr, const half8_t* w1f) {  // T1T[(t*48+j)][i], f16
        _Float16* t1 = ldsH + ((rr & 1) ? T1B_H : T1A_H);
        #pragma unroll
        for (int ct = 0; ct < 3; ++ct) {
            const f32x4_t c0 = __builtin_amdgcn_mfma_f32_16x16x32_f16(xp0, w1f[ct], zero4, 0, 0, 0);
            const f32x4_t c1 = __builtin_amdgcn_mfma_f32_16x16x32_f16(xp1, w1f[ct], zero4, 0, 0, 0);
            const int s = w * 48 + ct * 16 + l16;   // (t=w, j) row of T1T
            half4_t p;
            p[0] = (_Float16)c0[0]; p[1] = (_Float16)c0[1];
            p[2] = (_Float16)c0[2]; p[3] = (_Float16)c0[3];
            *(half4_t*)&t1[s * 40 + quad * 4] = p;
            p[0] = (_Float16)c1[0]; p[1] = (_Float16)c1[1];
            p[2] = (_Float16)c1[2]; p[3] = (_Float16)c1[3];
            *(half4_t*)&t1[s * 40 + 16 + quad * 4] = p;
        }
    };

    auto stage2 = [&](int rr, half8_t af) {   // hacc += (A1_r*64) * T1_r
        const _Float16* t1 = ldsH + ((rr & 1) ? T1B_H : T1A_H);
        #pragma unroll
        for (int u = 0; u < 12; ++u) {
            const int ct = (w >> 2) + 2 * u;
            const half8_t bf = *(const half8_t*)&t1[(ct * 16 + l16) * 40 + quad * 8];
            hacc[u] = __builtin_amdgcn_mfma_f32_16x16x32_f16(af, bf, hacc[u], 0, 0, 0);
        }
    };

    // ---------------- phase A: 1 barrier per r, T1 dbuf, W prefetched --------
    half8_t w1x[2][3];
    half8_t w2x[2];
    #pragma unroll
    for (int ct = 0; ct < 3; ++ct) w1x[0][ct] = w1load(0, ct);
    w2x[0] = w2load(0);
    stage1(0, w1x[0]);
    #pragma unroll
    for (int ct = 0; ct < 3; ++ct) w1x[1][ct] = w1load(1, ct);
    w2x[1] = w2load(1);
    __syncthreads();
    #pragma unroll
    for (int r = 0; r < R_; ++r) {
        stage2(r, w2x[r & 1]);
        if (r + 1 < R_) stage1(r + 1, w1x[(r + 1) & 1]);
        if (r + 2 < R_) {            // prefetch r+2 into the retiring slot
            #pragma unroll
            for (int ct = 0; ct < 3; ++ct) w1x[r & 1][ct] = w1load(r + 2, ct);
            w2x[r & 1] = w2load(r + 2);
        }
        __syncthreads();
    }

    // ---------------- epilogue: h = hacc/4096 + b1; HgT = gelu(h)*4096 -------
    {
        const float inv4096 = 1.0f / 4096.0f;
        #pragma unroll
        for (int u = 0; u < 12; ++u) {
            const int ct = (w >> 2) + 2 * u;
            const int s  = ct * 16 + l16;           // (t,n2) in [0,384)
            const int n2 = s % 48;
            const int n1b = (w & 3) * 16 + quad * 4;
            half4_t p;
            #pragma unroll
            for (int rg = 0; rg < 4; ++rg) {
                const float hv = hacc[u][rg] * inv4096 + b1[(n1b + rg) * 48 + n2];
                float g;
                if (__builtin_expect(fabsf(hv) < 0.04f, 1)) {
                    g = fmaf(0.3989422804f * hv, hv, 0.5f * hv);  // |err| = O(h^4)
                } else {
                    g = 0.5f * hv * (1.0f + erff(hv * 0.70710678118654752f));
                }
                p[rg] = (_Float16)(g * 4096.0f);
            }
            *(half4_t*)&ldsH[HG_H + s * 72 + n1b] = p;   // HgT[(t,n2)][n1]
        }
    }

    // ---------------- phase-B hoists (token-invariant, register-resident) ----
    const int kh  = w >> 2;        // stage-4 k-half (r 0..3 | 4..7)
    const int rt4 = (w >> 1) & 1;  // stage-4 m1 tile
    const int ct4 = w & 1;         // stage-4 m2 tile
    const float sc = 1.0f / 16777216.0f;   // 2^-24

    // stage-3 B-operand (A2 rows = m1); wave w owns r=w
    half8_t w3f[2][2];
    #pragma unroll
    for (int e = 0; e < 2; ++e)
        #pragma unroll
        for (int kk = 0; kk < 2; ++kk)
            w3f[e][kk] = *(const half8_t*)&W[W3_OFF + (w * 32 + e * 16 + l16) * 64 + kk * 32 + quad * 8];

    // stage-4 A-operand (B2 rows = m2), K-half kh
    half8_t w4f[6];
    #pragma unroll
    for (int kk = 0; kk < 6; ++kk)
        w4f[kk] = *(const half8_t*)&W[W4_OFF + (ct4 * 16 + l16) * 384 + kh * 192 + kk * 32 + quad * 8];

    // final-store q/b2 (token-invariant)
    const int  qa = idx64 ? q[2 * tid] : q[tid];
    const float ba = b2[qa];
    const bool has2 = tid < DIN - 512;
    int qb = 0; float bb = 0.f;
    if (has2) {
        qb = idx64 ? q[2 * (512 + tid)] : q[512 + tid];
        bb = b2[qb];
    }
    __syncthreads();

    // ---------------- phase B per token ---------------------------------------
    // stage 3 (swapped): D[(t,n2)][m1] = Hg' x (A2*64): lane holds 4 consecutive
    // n2 at fixed m1 -> one b64 scatter per tile into Z'[m1][r*48+n2].
    // stage 4 (swapped): D[m2][m1] = (B2'*64) x Z': lane holds 4 consecutive m2
    // at fixed m1 -> one masked b128 write into P[kh][m1*24+m2].
    for (int tt = 0; tt < T_TOK; ++tt) {
        f32x4_t zc[6];
        #pragma unroll
        for (int u = 0; u < 6; ++u) zc[u] = zero4;
        #pragma unroll
        for (int ct = 0; ct < 3; ++ct)
            #pragma unroll
            for (int kk = 0; kk < 2; ++kk) {
                const half8_t af = *(const half8_t*)&ldsH[HG_H + (tt * 48 + ct * 16 + l16) * 72 + kk * 32 + quad * 8];
                #pragma unroll
                for (int e = 0; e < 2; ++e) {
                    const int u = ct * 2 + e;
                    zc[u] = __builtin_amdgcn_mfma_f32_16x16x32_f16(af, w3f[e][kk], zc[u], 0, 0, 0);
                }
            }
        // scatter: Z'[m1 = e*16+l16][w*48 + ct*16 + quad*4 + rg], b64 each
        #pragma unroll
        for (int ct = 0; ct < 3; ++ct)
            #pragma unroll
            for (int e = 0; e < 2; ++e) {
                const int u = ct * 2 + e;
                half4_t p;
                p[0] = (_Float16)zc[u][0]; p[1] = (_Float16)zc[u][1];
                p[2] = (_Float16)zc[u][2]; p[3] = (_Float16)zc[u][3];
                *(half4_t*)&ldsH[ZP_H + (e * 16 + l16) * 392 + w * 48 + ct * 16 + quad * 4] = p;
            }
        __syncthreads();   // scatter visible; all stage-3 reads of HG slab tt done

        // stage 4: oc = (B2'*64) x Z'  (K-half = 192 per wave)
        f32x4_t oc = zero4;
        #pragma unroll
        for (int kk = 0; kk < 6; ++kk) {
            const half8_t zf = *(const half8_t*)&ldsH[ZP_H + (rt4 * 16 + l16) * 392 + kh * 192 + kk * 32 + quad * 8];
            oc = __builtin_amdgcn_mfma_f32_16x16x32_f16(w4f[kk], zf, oc, 0, 0, 0);
        }
        // P[kh][m1*24+m2], contiguous 4 m2 -> b128; slab tt (1728 f32)
        {
            const int m2b = ct4 * 16 + quad * 4;
            if (m2b < M2_) {
                *(f32x4_t*)&ldsF[1728 * tt + kh * 768 + (rt4 * 16 + l16) * 24 + m2b] = oc;
            }
        }
        __syncthreads();   // partials visible; ZP free for next tt

        // per-token final: sum halves, *2^-24, +b2, q-gather, coalesced store
        {
            const float* Pb = ldsF + 1728 * tt;
            float* orow = out + (size_t)(tokBase + tt) * DIN;
            orow[tid] = (Pb[qa] + Pb[768 + qa]) * sc + ba;
            if (has2)
                orow[512 + tid] = (Pb[qb] + Pb[768 + qb]) * sc + bb;
        }
        // next stage-3 touches HG slabs > tt and ZP only; safe without barrier
    }
}

} // namespace

extern "C" void kernel_launch(void* const* d_in, const int* in_sizes, int n_in,
                              void* d_out, int out_size, void* d_ws, size_t ws_size,
                              hipStream_t stream) {
    const float* x   = (const float*)d_in[0];
    const float* A1  = (const float*)d_in[1];
    const float* B1  = (const float*)d_in[2];
    const float* A2  = (const float*)d_in[3];
    const float* B2  = (const float*)d_in[4];
    const float* b1  = (const float*)d_in[5];
    const float* b2  = (const float*)d_in[6];
    const int*   piv = (const int*)d_in[7];
    const int*   q   = (const int*)d_in[8];
    float* out = (float*)d_out;
    _Float16* Wws = (_Float16*)d_ws;

    const int tokens = in_sizes[0] / DIN;          // 4096
    const int grid   = tokens / T_TOK;             // 512 = 2 per CU, 1 generation

    prep_weights<<<(W_TOTAL + 255) / 256, 256, 0, stream>>>(A1, B1, A2, B2, Wws);

    (void)hipFuncSetAttribute((const void*)kn_mfma,
                              hipFuncAttributeMaxDynamicSharedMemorySize,
                              LDS_BYTES);
    kn_mfma<<<grid, NTHREADS, LDS_BYTES, stream>>>(x, b1, b2, piv, q, Wws, out);
}